// Round 17
// baseline (328.413 us; speedup 1.0000x reference)
//
#include <hip/hip_runtime.h>
#include <hip/hip_bf16.h>

// GraphSAGE 2-layer + BN + ReLU + MLP classifier.
// R17: aggregate decode lightened — uint4 loads (8 lanes/row, 16B/lane),
//      f32x2 accumulators (pk_add), 16 edges/iter. R16 pipeline otherwise.

#define HID 128
#define CHUNK 1536   // 256 threads x 6 edges
#define NBKT 128     // total sub-buckets (8 XCD ranges x 16)

typedef __attribute__((ext_vector_type(8))) short short8;
typedef __attribute__((ext_vector_type(4))) float f32x4;
typedef __attribute__((ext_vector_type(2))) float f32x2;

union FragU { uint4 u; short8 s; };

#if defined(__has_builtin)
#if __has_builtin(__builtin_amdgcn_cvt_pk_f32_fp8) && __has_builtin(__builtin_amdgcn_cvt_pk_fp8_f32)
#define HAVE_FP8_CVT 1
#endif
#endif

__device__ inline uint32_t pack_bf16(float a, float b) {
    uint32_t ua = __float_as_uint(a);
    uint32_t ub = __float_as_uint(b);
    ua = ua + 0x7fffu + ((ua >> 16) & 1u);  // RNE
    ub = ub + 0x7fffu + ((ub >> 16) & 1u);
    return (ua >> 16) | (ub & 0xffff0000u);
}

__device__ inline unsigned short bf16_one(float a) {
    uint32_t u = __float_as_uint(a);
    u = u + 0x7fffu + ((u >> 16) & 1u);
    return (unsigned short)(u >> 16);
}

// ---- fp8 e4m3fn encode/decode (manual fallbacks for safety) ----
__device__ inline unsigned char enc_e4m3(float f) {
    unsigned char s = (f < 0.f) ? 0x80 : 0;
    float a = fabsf(f);
    if (a >= 448.f) return s | 0x7E;
    if (a < 9.765625e-4f) return s;  // < 2^-10 -> 0
    int e; float m = frexpf(a, &e);  // a = m*2^e, m in [0.5,1)
    int E = e + 6;
    if (E <= 0) {
        int m3 = (int)rintf(ldexpf(a, 9));
        if (m3 > 7) return s | 0x08;
        return s | (unsigned char)m3;
    }
    int m3 = (int)rintf((m - 0.5f) * 16.f);
    if (m3 == 8) { E += 1; m3 = 0; if (E >= 16) return s | 0x7E; }
    return s | (unsigned char)((E << 3) | m3);
}

__device__ inline float dec_e4m3(unsigned char u) {
    int E = (u >> 3) & 0xF, m = u & 7;
    float v = E ? __uint_as_float((uint32_t)(((E + 120) << 23) | (m << 20)))
                : (float)m * 1.953125e-3f;
    return (u & 0x80) ? -v : v;
}

__device__ inline uint32_t pack_fp8x4(float a, float b, float c, float d) {
#ifdef HAVE_FP8_CVT
    int r = 0;
    r = __builtin_amdgcn_cvt_pk_fp8_f32(a, b, r, false);
    r = __builtin_amdgcn_cvt_pk_fp8_f32(c, d, r, true);
    return (uint32_t)r;
#else
    return (uint32_t)enc_e4m3(a) | ((uint32_t)enc_e4m3(b) << 8) |
           ((uint32_t)enc_e4m3(c) << 16) | ((uint32_t)enc_e4m3(d) << 24);
#endif
}

// decode one dword (4 fp8) into two f32x2 accumulators
__device__ inline void add_fp8x4_v(f32x2* a0, f32x2* a1, uint32_t u) {
#ifdef HAVE_FP8_CVT
    f32x2 lo = __builtin_amdgcn_cvt_pk_f32_fp8((int)u, false);
    f32x2 hi = __builtin_amdgcn_cvt_pk_f32_fp8((int)u, true);
    *a0 += lo;
    *a1 += hi;
#else
    f32x2 lo = {dec_e4m3(u & 255), dec_e4m3((u >> 8) & 255)};
    f32x2 hi = {dec_e4m3((u >> 16) & 255), dec_e4m3(u >> 24)};
    *a0 += lo;
    *a1 += hi;
#endif
}

// ---- phase 1: bin edges into 128 node-range buckets ----
__global__ __launch_bounds__(256) void bin_kernel(
    const int* __restrict__ src, const int* __restrict__ tgt,
    int* __restrict__ gcount, int2* __restrict__ bpairs,
    int e, int npb, int npb2, int cap) {
    __shared__ int2 pairs[CHUNK];
    __shared__ unsigned char bkt[CHUNK];
    __shared__ int lcnt[NBKT], lbase[NBKT], lpos[NBKT];
    int tid = threadIdx.x;
    if (tid < NBKT) { lcnt[tid] = 0; lpos[tid] = 0; }
    __syncthreads();
    int chunk0 = blockIdx.x * CHUNK;
    #pragma unroll
    for (int j = 0; j < 6; ++j) {
        int k = tid + j * 256;
        int idx = chunk0 + k;
        if (idx < e) {
            int s = src[idx];
            int t = tgt[idx];
            int x = t / npb;
            int jj = (t - x * npb) / npb2;
            if (jj > 15) jj = 15;
            int b = x * 16 + jj;
            pairs[k] = make_int2(s, t);
            bkt[k] = (unsigned char)b;
            atomicAdd(&lcnt[b], 1);
        }
    }
    __syncthreads();
    if (tid < NBKT) lbase[tid] = atomicAdd(&gcount[tid * 32], lcnt[tid]);
    __syncthreads();
    #pragma unroll
    for (int j = 0; j < 6; ++j) {
        int k = tid + j * 256;
        int idx = chunk0 + k;
        if (idx < e) {
            int b = bkt[k];
            int r = atomicAdd(&lpos[b], 1);
            bpairs[(size_t)b * cap + lbase[b] + r] = pairs[k];
        }
    }
}

// ---- phase 2: one 1024-thread block per bucket; LDS hist+scan -> off, csr ----
__global__ __launch_bounds__(1024) void build_kernel(
    const int2* __restrict__ bpairs, const int* __restrict__ gcount,
    int* __restrict__ off, int* __restrict__ csr,
    int cap, int npb, int npb2, int n, int e) {
    __shared__ int ldeg[1024];
    __shared__ int loff[1024];
    __shared__ int wsum[16], wpre[16];
    __shared__ int bbase;
    int tid = threadIdx.x;
    int lane = tid & 63, wid = tid >> 6;
    int b = blockIdx.x;          // 128 blocks
    int x = b & 7, j = b >> 3;
    int bucket = x * 16 + j;
    int lo = x * npb + j * npb2;
    int xhi = min((x + 1) * npb, n);
    int hi = min(lo + npb2, xhi);
    if (hi < lo) hi = lo;
    int nn = hi - lo;            // <= npb2 (782) <= 1024
    int cntb = gcount[bucket * 32];
    const int2* bp = bpairs + (size_t)bucket * cap;
    {
        int part = 0;
        for (int q = tid; q < bucket; q += 1024) part += gcount[q * 32];
        #pragma unroll
        for (int o = 1; o < 64; o <<= 1) part += __shfl_xor(part, o, 64);
        if (lane == 0) wsum[wid] = part;
    }
    ldeg[tid] = 0;
    __syncthreads();
    if (tid == 0) {
        int c = 0;
        #pragma unroll
        for (int w = 0; w < 16; ++w) c += wsum[w];
        bbase = c;
    }
    __syncthreads();
    for (int i = tid; i < cntb; i += 1024) atomicAdd(&ldeg[bp[i].y - lo], 1);
    __syncthreads();
    int v = (tid < nn) ? ldeg[tid] : 0;
    int s = v;
    #pragma unroll
    for (int o = 1; o < 64; o <<= 1) {
        int t = __shfl_up(s, o, 64);
        if (lane >= o) s += t;
    }
    if (lane == 63) wsum[wid] = s;
    __syncthreads();
    if (tid == 0) {
        int c = 0;
        #pragma unroll
        for (int w = 0; w < 16; ++w) { wpre[w] = c; c += wsum[w]; }
    }
    __syncthreads();
    int excl = wpre[wid] + s - v;
    int base = bbase;
    if (tid < nn) {
        loff[tid] = excl;
        off[lo + tid] = base + excl;
    }
    if (b == 0 && tid == 0) off[n] = e;
    __syncthreads();
    ldeg[tid] = 0;
    __syncthreads();
    for (int i = tid; i < cntb; i += 1024) {
        int2 p = bp[i];
        int k = p.y - lo;
        int slot = base + loff[k] + atomicAdd(&ldeg[k], 1);
        csr[slot] = p.x;
    }
}

// x -> bf16 table (sage x-path) + fp8 table (gather). 4 cols/thread.
__global__ void cvt_x_kernel(const float* __restrict__ in, uint32_t* __restrict__ bfout,
                             uint32_t* __restrict__ f8out, int n4) {
    int i = blockIdx.x * blockDim.x + threadIdx.x;
    if (i >= n4) return;
    float4 v = ((const float4*)in)[i];
    bfout[i * 2]     = pack_bf16(v.x, v.y);
    bfout[i * 2 + 1] = pack_bf16(v.z, v.w);
    f8out[i] = pack_fp8x4(v.x, v.y, v.z, v.w);
}

// Pack [Wn;Wr] into MFMA B-frag bf16 layout (see R5).
__global__ void pack_w_kernel(const float* __restrict__ Wn, const float* __restrict__ Wr,
                              uint32_t* __restrict__ packed) {
    int t = blockIdx.x * blockDim.x + threadIdx.x;  // 4096 threads
    if (t >= 4096) return;
    int lane = t & 63;
    int no = (t >> 6) & 7;
    int ko = t >> 9;
    int n = no * 16 + (lane & 15);
    int kbase = ko * 32 + ((lane >> 4) << 3);
    uint32_t v[4];
    #pragma unroll
    for (int jj = 0; jj < 4; ++jj) {
        int k0 = kbase + jj * 2, k1 = k0 + 1;
        float a = (k0 < 128) ? Wn[k0 * 128 + n] : Wr[(k0 - 128) * 128 + n];
        float b = (k1 < 128) ? Wn[k1 * 128 + n] : Wr[(k1 - 128) * 128 + n];
        v[jj] = pack_bf16(a, b);
    }
    uint4 u4; u4.x = v[0]; u4.y = v[1]; u4.z = v[2]; u4.w = v[3];
    ((uint4*)packed)[t] = u4;
}

// Pack Wc1 [128][64] f32 into B-frag layout
__global__ void pack_wc_kernel(const float* __restrict__ Wc1, uint32_t* __restrict__ packed) {
    int t = blockIdx.x * blockDim.x + threadIdx.x;  // 1024 threads
    if (t >= 1024) return;
    int lane = t & 63;
    int no = (t >> 6) & 3;
    int ko = t >> 8;
    int n = no * 16 + (lane & 15);
    int kbase = ko * 32 + ((lane >> 4) << 3);
    uint32_t v[4];
    #pragma unroll
    for (int jj = 0; jj < 4; ++jj) {
        int k0 = kbase + jj * 2;
        v[jj] = pack_bf16(Wc1[k0 * 64 + n], Wc1[(k0 + 1) * 64 + n]);
    }
    uint4 u4; u4.x = v[0]; u4.y = v[1]; u4.z = v[2]; u4.w = v[3];
    ((uint4*)packed)[t] = u4;
}

// one wave per node; fp8 rows (128B): 8 lanes x uint4 per row, 8 edges/group,
// unrolled x2 (16 edges/iter). f32x2 accumulators (pk_add). Wave-uniform shfl.
__global__ __launch_bounds__(256) void aggregate_fp8_kernel(
    const uint32_t* __restrict__ f8, const int* __restrict__ off,
    const int* __restrict__ csr, uint32_t* __restrict__ outmean, int n) {
    int wv = (blockIdx.x * blockDim.x + threadIdx.x) >> 6;
    int lane = threadIdx.x & 63;
    if (wv >= n) return;
    int beg = off[wv], end = off[wv + 1];
    int len = end - beg;
    int sub = lane >> 3;   // 0..7: which of 8 concurrent edges
    int c   = lane & 7;    // uint4 chunk: cols c*16 .. c*16+15
    const uint4* fp = (const uint4*)f8;  // row = 8 uint4
    f32x2 acc[8];
    #pragma unroll
    for (int k = 0; k < 8; ++k) acc[k] = (f32x2){0.f, 0.f};
    for (int base = 0; base < len; base += 64) {
        int m = len - base; if (m > 64) m = 64;
        int idx = csr[beg + base + (lane < m ? lane : 0)];
        for (int j0 = 0; j0 < m; j0 += 16) {          // wave-uniform trip count
            int ja = j0 + sub;
            int jb = j0 + 8 + sub;
            int sa = __shfl(idx, (ja < m ? ja : 0), 64);  // all lanes active
            int sb = __shfl(idx, (jb < m ? jb : 0), 64);
            bool pa = ja < m, pb = jb < m;
            uint4 ua, ub;
            if (pa) ua = fp[(size_t)sa * 8 + c];
            if (pb) ub = fp[(size_t)sb * 8 + c];
            if (pa) {
                add_fp8x4_v(&acc[0], &acc[1], ua.x);
                add_fp8x4_v(&acc[2], &acc[3], ua.y);
                add_fp8x4_v(&acc[4], &acc[5], ua.z);
                add_fp8x4_v(&acc[6], &acc[7], ua.w);
            }
            if (pb) {
                add_fp8x4_v(&acc[0], &acc[1], ub.x);
                add_fp8x4_v(&acc[2], &acc[3], ub.y);
                add_fp8x4_v(&acc[4], &acc[5], ub.z);
                add_fp8x4_v(&acc[6], &acc[7], ub.w);
            }
        }
    }
    // reduce across the 8 sub-groups (lanes c, c+8, ..., c+56)
    #pragma unroll
    for (int k = 0; k < 8; ++k) {
        #pragma unroll
        for (int o = 8; o < 64; o <<= 1) {
            acc[k].x += __shfl_xor(acc[k].x, o, 64);
            acc[k].y += __shfl_xor(acc[k].y, o, 64);
        }
    }
    float inv = 1.0f / fmaxf((float)len, 1.0f);
    // lane (c,sub) writes bf16 dword c*8+sub = cols c*16+2*sub, c*16+2*sub+1
    outmean[(size_t)wv * 64 + c * 8 + sub] =
        pack_bf16(acc[sub].x * inv, acc[sub].y * inv);
}

// h = [mean|x](bf16) @ Wpacked + b via MFMA; writes h_raw as BF16.
__global__ __launch_bounds__(256) void sage_mfma_kernel(
    const uint32_t* __restrict__ meanbf, const uint32_t* __restrict__ xbf,
    const uint32_t* __restrict__ Wp, const float* __restrict__ bias,
    unsigned short* __restrict__ hout, float* __restrict__ stats, int n) {
    __shared__ uint4 sW[4096];          // 64 KB packed weights
    __shared__ float redS[4][128];
    __shared__ float redQ[4][128];
    for (int i = threadIdx.x; i < 4096; i += 256) sW[i] = ((const uint4*)Wp)[i];
    __syncthreads();
    int lane = threadIdx.x & 63;
    int wid = threadIdx.x >> 6;
    int c = lane & 15;
    int kg = lane >> 4;
    float bcol[8];
    #pragma unroll
    for (int no = 0; no < 8; ++no) bcol[no] = bias[no * 16 + c];
    float ssum[8], ssq[8];
    #pragma unroll
    for (int no = 0; no < 8; ++no) { ssum[no] = 0.f; ssq[no] = 0.f; }
    int nstrips = n >> 4;
    int sstride = gridDim.x * 4;
    for (int strip = blockIdx.x * 4 + wid; strip < nstrips; strip += sstride) {
        const uint4* mrow = (const uint4*)(meanbf + (size_t)(strip * 16 + c) * 64);
        const uint4* xrow = (const uint4*)(xbf + (size_t)(strip * 16 + c) * 64);
        f32x4 acc[8];
        #pragma unroll
        for (int no = 0; no < 8; ++no) acc[no] = (f32x4){0.f, 0.f, 0.f, 0.f};
        #pragma unroll
        for (int ko = 0; ko < 8; ++ko) {
            FragU a;
            a.u = (ko < 4) ? mrow[ko * 4 + kg] : xrow[(ko - 4) * 4 + kg];
            #pragma unroll
            for (int no = 0; no < 8; ++no) {
                FragU b;
                b.u = sW[(ko * 8 + no) * 64 + lane];
                acc[no] = __builtin_amdgcn_mfma_f32_16x16x32_bf16(a.s, b.s, acc[no], 0, 0, 0);
            }
        }
        #pragma unroll
        for (int no = 0; no < 8; ++no) {
            #pragma unroll
            for (int r = 0; r < 4; ++r) {
                float v = acc[no][r] + bcol[no];
                int grow = strip * 16 + kg * 4 + r;
                hout[(size_t)grow * HID + no * 16 + c] = bf16_one(v);
                ssum[no] += v;
                ssq[no] += v * v;
            }
        }
    }
    #pragma unroll
    for (int no = 0; no < 8; ++no) {
        ssum[no] += __shfl_xor(ssum[no], 16, 64);
        ssum[no] += __shfl_xor(ssum[no], 32, 64);
        ssq[no]  += __shfl_xor(ssq[no], 16, 64);
        ssq[no]  += __shfl_xor(ssq[no], 32, 64);
    }
    if (lane < 16) {
        #pragma unroll
        for (int no = 0; no < 8; ++no) {
            redS[wid][no * 16 + lane] = ssum[no];
            redQ[wid][no * 16 + lane] = ssq[no];
        }
    }
    __syncthreads();
    if (threadIdx.x < 128) {
        float ts = redS[0][threadIdx.x] + redS[1][threadIdx.x] + redS[2][threadIdx.x] + redS[3][threadIdx.x];
        float tq = redQ[0][threadIdx.x] + redQ[1][threadIdx.x] + redQ[2][threadIdx.x] + redQ[3][threadIdx.x];
        atomicAdd(&stats[threadIdx.x], ts);
        atomicAdd(&stats[HID + threadIdx.x], tq);
    }
}

__global__ void bnparam_kernel(const float* __restrict__ stats, const float* __restrict__ g,
                               const float* __restrict__ be, float* __restrict__ params, float invn) {
    int j = threadIdx.x;  // 128
    float mu = stats[j] * invn;
    float var = stats[HID + j] * invn - mu * mu;
    float a = g[j] * rsqrtf(var + 1e-5f);
    params[j] = a;
    params[HID + j] = be[j] - mu * a;
}

// read bf16 h_raw (4 cols/thread), normalize+relu, write bf16 (+ optional fp8)
__global__ void norm_relu_kernel(const uint32_t* __restrict__ hraw, uint32_t* __restrict__ hbf,
                                 uint32_t* __restrict__ f8out, const float* __restrict__ params,
                                 int total4) {
    int i = blockIdx.x * blockDim.x + threadIdx.x;
    if (i >= total4) return;
    int cp = (i & 31) * 4;  // first col of this 4-col group
    uint2 u = ((const uint2*)hraw)[i];
    float v0 = __uint_as_float(u.x << 16);
    float v1 = __uint_as_float(u.x & 0xffff0000u);
    float v2 = __uint_as_float(u.y << 16);
    float v3 = __uint_as_float(u.y & 0xffff0000u);
    v0 = fmaxf(fmaf(v0, params[cp], params[HID + cp]), 0.f);
    v1 = fmaxf(fmaf(v1, params[cp + 1], params[HID + cp + 1]), 0.f);
    v2 = fmaxf(fmaf(v2, params[cp + 2], params[HID + cp + 2]), 0.f);
    v3 = fmaxf(fmaf(v3, params[cp + 3], params[HID + cp + 3]), 0.f);
    uint2 w;
    w.x = pack_bf16(v0, v1);
    w.y = pack_bf16(v2, v3);
    ((uint2*)hbf)[i] = w;
    if (f8out) f8out[i] = pack_fp8x4(v0, v1, v2, v3);
}

// classifier via MFMA: out = relu(hn@Wc1+bc1)@Wc2 + bc2.
__global__ __launch_bounds__(256) void classifier_mfma_kernel(
    const uint32_t* __restrict__ hnbf, const uint32_t* __restrict__ Wcp,
    const float* __restrict__ bc1, const float* __restrict__ Wc2,
    const float* __restrict__ bc2, float* __restrict__ out, int n) {
    __shared__ uint4 sW[1024];  // 16 KB packed Wc1
    for (int i = threadIdx.x; i < 1024; i += 256) sW[i] = ((const uint4*)Wcp)[i];
    __syncthreads();
    int lane = threadIdx.x & 63;
    int wid = threadIdx.x >> 6;
    int c = lane & 15;
    int kg = lane >> 4;
    float b1v[4], w2v[4];
    #pragma unroll
    for (int no = 0; no < 4; ++no) {
        b1v[no] = bc1[no * 16 + c];
        w2v[no] = Wc2[no * 16 + c];
    }
    float b2v = bc2[0];
    int nstrips = n >> 4;
    int sstride = gridDim.x * 4;
    for (int strip = blockIdx.x * 4 + wid; strip < nstrips; strip += sstride) {
        const uint4* hrow = (const uint4*)(hnbf + (size_t)(strip * 16 + c) * 64);
        f32x4 acc[4];
        #pragma unroll
        for (int no = 0; no < 4; ++no) acc[no] = (f32x4){0.f, 0.f, 0.f, 0.f};
        #pragma unroll
        for (int ko = 0; ko < 4; ++ko) {
            FragU a;
            a.u = hrow[ko * 4 + kg];
            #pragma unroll
            for (int no = 0; no < 4; ++no) {
                FragU b;
                b.u = sW[(ko * 4 + no) * 64 + lane];
                acc[no] = __builtin_amdgcn_mfma_f32_16x16x32_bf16(a.s, b.s, acc[no], 0, 0, 0);
            }
        }
        float p[4];
        #pragma unroll
        for (int r = 0; r < 4; ++r) {
            p[r] = 0.f;
            #pragma unroll
            for (int no = 0; no < 4; ++no)
                p[r] += fmaxf(acc[no][r] + b1v[no], 0.f) * w2v[no];
        }
        #pragma unroll
        for (int r = 0; r < 4; ++r) {
            p[r] += __shfl_xor(p[r], 1, 64);
            p[r] += __shfl_xor(p[r], 2, 64);
            p[r] += __shfl_xor(p[r], 4, 64);
            p[r] += __shfl_xor(p[r], 8, 64);
        }
        if (c == 0) {
            int row = strip * 16 + kg * 4;
            #pragma unroll
            for (int r = 0; r < 4; ++r) out[row + r] = p[r] + b2v;
        }
    }
}

extern "C" void kernel_launch(void* const* d_in, const int* in_sizes, int n_in,
                              void* d_out, int out_size, void* d_ws, size_t ws_size,
                              hipStream_t stream) {
    const float* x   = (const float*)d_in[0];
    const int*   ei  = (const int*)d_in[1];
    const float* Wn0 = (const float*)d_in[2];
    const float* b0  = (const float*)d_in[3];
    const float* Wr0 = (const float*)d_in[4];
    const float* g0  = (const float*)d_in[5];
    const float* be0 = (const float*)d_in[6];
    const float* Wn1 = (const float*)d_in[7];
    const float* b1  = (const float*)d_in[8];
    const float* Wr1 = (const float*)d_in[9];
    const float* g1  = (const float*)d_in[10];
    const float* be1 = (const float*)d_in[11];
    const float* Wc1 = (const float*)d_in[12];
    const float* bc1 = (const float*)d_in[13];
    const float* Wc2 = (const float*)d_in[14];
    const float* bc2 = (const float*)d_in[15];
    float* out = (float*)d_out;

    const int N = in_sizes[0] / HID;
    const int E = in_sizes[1] / 2;
    const int* srcv = ei;
    const int* tgtv = ei + E;

    size_t o = 0;
    auto carve = [&](size_t bytes) {
        void* p = (char*)d_ws + o;
        o += (bytes + 255) & ~(size_t)255;
        return p;
    };
    int* off       = (int*)carve((size_t)(N + 1) * 4);
    int* csr       = (int*)carve((size_t)E * 4);
    float* bufA    = (float*)carve((size_t)N * HID * 4);   // [mean0|h0raw] then [h1raw|-]
    float* bufB    = (float*)carve((size_t)N * HID * 4);   // bpairs, then mean1
    uint32_t* fbf  = (uint32_t*)carve((size_t)N * HID * 2);  // bf16: x, h0n, then h1n
    uint32_t* f8t  = (uint32_t*)carve((size_t)N * HID);      // fp8 gather table: x, then h0n
    uint32_t* Wp0  = (uint32_t*)carve(4096 * 16);
    uint32_t* Wp1  = (uint32_t*)carve(4096 * 16);
    uint32_t* Wcp  = (uint32_t*)carve(1024 * 16);
    int* gcount    = (int*)carve(NBKT * 128);  // counters padded to 128B lines
    float* stats0  = (float*)carve(256 * 4);
    float* stats1  = (float*)carve(256 * 4);
    float* params0 = (float*)carve(256 * 4);
    float* params1 = (float*)carve(256 * 4);
    (void)ws_size; (void)n_in; (void)out_size;

    uint32_t* mean0 = (uint32_t*)bufA;                          // bufA first half
    uint32_t* h0raw = (uint32_t*)bufA + (size_t)N * 64;         // bufA second half
    uint32_t* mean1 = (uint32_t*)bufB;                          // bpairs dead
    uint32_t* h1raw = (uint32_t*)bufA;                          // mean0 dead
    int2* bpairs    = (int2*)bufB;

    const int npb  = (N + 7) / 8;        // nodes per XCD range
    const int npb2 = (npb + 15) / 16;    // nodes per sub-bucket
    const int cap  = E / NBKT + 4096;    // per-bucket capacity (slack)

    hipMemsetAsync(gcount, 0, NBKT * 128, stream);
    hipMemsetAsync(stats0, 0, 256 * 4, stream);
    hipMemsetAsync(stats1, 0, 256 * 4, stream);

    int binblocks = (E + CHUNK - 1) / CHUNK;

    bin_kernel<<<binblocks, 256, 0, stream>>>(srcv, tgtv, gcount, bpairs, E, npb, npb2, cap);
    build_kernel<<<NBKT, 1024, 0, stream>>>(bpairs, gcount, off, csr, cap, npb, npb2, N, E);

    pack_w_kernel<<<16, 256, 0, stream>>>(Wn0, Wr0, Wp0);
    pack_w_kernel<<<16, 256, 0, stream>>>(Wn1, Wr1, Wp1);
    pack_wc_kernel<<<4, 256, 0, stream>>>(Wc1, Wcp);

    int aggblocks = (N * 64 + 255) / 256;
    int q4blocks  = (N * 32 + 255) / 256;
    float invn = 1.0f / (float)N;

    // layer 0
    cvt_x_kernel<<<q4blocks, 256, 0, stream>>>(x, fbf, f8t, N * 32);
    aggregate_fp8_kernel<<<aggblocks, 256, 0, stream>>>(f8t, off, csr, mean0, N);
    sage_mfma_kernel<<<256, 256, 0, stream>>>(mean0, fbf, Wp0, b0, (unsigned short*)h0raw, stats0, N);
    bnparam_kernel<<<1, 128, 0, stream>>>(stats0, g0, be0, params0, invn);
    norm_relu_kernel<<<q4blocks, 256, 0, stream>>>(h0raw, fbf, f8t, params0, N * 32);

    // layer 1
    aggregate_fp8_kernel<<<aggblocks, 256, 0, stream>>>(f8t, off, csr, mean1, N);
    sage_mfma_kernel<<<256, 256, 0, stream>>>(mean1, fbf, Wp1, b1, (unsigned short*)h1raw, stats1, N);
    bnparam_kernel<<<1, 128, 0, stream>>>(stats1, g1, be1, params1, invn);
    norm_relu_kernel<<<q4blocks, 256, 0, stream>>>(h1raw, fbf, nullptr, params1, N * 32);

    // classifier (reads bf16 h1 from fbf)
    classifier_mfma_kernel<<<256, 256, 0, stream>>>(fbf, Wcp, bc1, Wc2, bc2, out, N);
}

// Round 18
// 321.976 us; speedup vs baseline: 1.0200x; 1.0200x over previous
//
#include <hip/hip_runtime.h>
#include <hip/hip_bf16.h>

// GraphSAGE 2-layer + BN + ReLU + MLP classifier.
// R18: revert aggregate to R16 16-lane/uint2 layout (R17's 8-lane regressed);
//      decode kept fully packed: 2x cvt_pk + 2x f32x2 add per dword, f32x2
//      accumulators end-to-end (pk_add). Rest of pipeline = R16.

#define HID 128
#define CHUNK 1536   // 256 threads x 6 edges
#define NBKT 128     // total sub-buckets (8 XCD ranges x 16)

typedef __attribute__((ext_vector_type(8))) short short8;
typedef __attribute__((ext_vector_type(4))) float f32x4;
typedef __attribute__((ext_vector_type(2))) float f32x2;

union FragU { uint4 u; short8 s; };

#if defined(__has_builtin)
#if __has_builtin(__builtin_amdgcn_cvt_pk_f32_fp8) && __has_builtin(__builtin_amdgcn_cvt_pk_fp8_f32)
#define HAVE_FP8_CVT 1
#endif
#endif

__device__ inline uint32_t pack_bf16(float a, float b) {
    uint32_t ua = __float_as_uint(a);
    uint32_t ub = __float_as_uint(b);
    ua = ua + 0x7fffu + ((ua >> 16) & 1u);  // RNE
    ub = ub + 0x7fffu + ((ub >> 16) & 1u);
    return (ua >> 16) | (ub & 0xffff0000u);
}

__device__ inline unsigned short bf16_one(float a) {
    uint32_t u = __float_as_uint(a);
    u = u + 0x7fffu + ((u >> 16) & 1u);
    return (unsigned short)(u >> 16);
}

// ---- fp8 e4m3fn encode/decode ----
__device__ inline unsigned char enc_e4m3(float f) {
    unsigned char s = (f < 0.f) ? 0x80 : 0;
    float a = fabsf(f);
    if (a >= 448.f) return s | 0x7E;
    if (a < 9.765625e-4f) return s;  // < 2^-10 -> 0
    int e; float m = frexpf(a, &e);  // a = m*2^e, m in [0.5,1)
    int E = e + 6;
    if (E <= 0) {
        int m3 = (int)rintf(ldexpf(a, 9));
        if (m3 > 7) return s | 0x08;
        return s | (unsigned char)m3;
    }
    int m3 = (int)rintf((m - 0.5f) * 16.f);
    if (m3 == 8) { E += 1; m3 = 0; if (E >= 16) return s | 0x7E; }
    return s | (unsigned char)((E << 3) | m3);
}

__device__ inline float dec_e4m3(unsigned char u) {
    int E = (u >> 3) & 0xF, m = u & 7;
    float v = E ? __uint_as_float((uint32_t)(((E + 120) << 23) | (m << 20)))
                : (float)m * 1.953125e-3f;
    return (u & 0x80) ? -v : v;
}

__device__ inline uint32_t pack_fp8x4(float a, float b, float c, float d) {
#ifdef HAVE_FP8_CVT
    int r = 0;
    r = __builtin_amdgcn_cvt_pk_fp8_f32(a, b, r, false);
    r = __builtin_amdgcn_cvt_pk_fp8_f32(c, d, r, true);
    return (uint32_t)r;
#else
    return (uint32_t)enc_e4m3(a) | ((uint32_t)enc_e4m3(b) << 8) |
           ((uint32_t)enc_e4m3(c) << 16) | ((uint32_t)enc_e4m3(d) << 24);
#endif
}

// decode one dword (4 fp8) and accumulate into two f32x2 (fully packed path)
__device__ inline void add_fp8x4_v(f32x2* a0, f32x2* a1, uint32_t u) {
#ifdef HAVE_FP8_CVT
    f32x2 lo = __builtin_amdgcn_cvt_pk_f32_fp8((int)u, false);
    f32x2 hi = __builtin_amdgcn_cvt_pk_f32_fp8((int)u, true);
    *a0 += lo;
    *a1 += hi;
#else
    f32x2 lo = {dec_e4m3(u & 255), dec_e4m3((u >> 8) & 255)};
    f32x2 hi = {dec_e4m3((u >> 16) & 255), dec_e4m3(u >> 24)};
    *a0 += lo;
    *a1 += hi;
#endif
}

// ---- phase 1: bin edges into 128 node-range buckets ----
__global__ __launch_bounds__(256) void bin_kernel(
    const int* __restrict__ src, const int* __restrict__ tgt,
    int* __restrict__ gcount, int2* __restrict__ bpairs,
    int e, int npb, int npb2, int cap) {
    __shared__ int2 pairs[CHUNK];
    __shared__ unsigned char bkt[CHUNK];
    __shared__ int lcnt[NBKT], lbase[NBKT], lpos[NBKT];
    int tid = threadIdx.x;
    if (tid < NBKT) { lcnt[tid] = 0; lpos[tid] = 0; }
    __syncthreads();
    int chunk0 = blockIdx.x * CHUNK;
    #pragma unroll
    for (int j = 0; j < 6; ++j) {
        int k = tid + j * 256;
        int idx = chunk0 + k;
        if (idx < e) {
            int s = src[idx];
            int t = tgt[idx];
            int x = t / npb;
            int jj = (t - x * npb) / npb2;
            if (jj > 15) jj = 15;
            int b = x * 16 + jj;
            pairs[k] = make_int2(s, t);
            bkt[k] = (unsigned char)b;
            atomicAdd(&lcnt[b], 1);
        }
    }
    __syncthreads();
    if (tid < NBKT) lbase[tid] = atomicAdd(&gcount[tid * 32], lcnt[tid]);
    __syncthreads();
    #pragma unroll
    for (int j = 0; j < 6; ++j) {
        int k = tid + j * 256;
        int idx = chunk0 + k;
        if (idx < e) {
            int b = bkt[k];
            int r = atomicAdd(&lpos[b], 1);
            bpairs[(size_t)b * cap + lbase[b] + r] = pairs[k];
        }
    }
}

// ---- phase 2: one 1024-thread block per bucket; LDS hist+scan -> off, csr ----
__global__ __launch_bounds__(1024) void build_kernel(
    const int2* __restrict__ bpairs, const int* __restrict__ gcount,
    int* __restrict__ off, int* __restrict__ csr,
    int cap, int npb, int npb2, int n, int e) {
    __shared__ int ldeg[1024];
    __shared__ int loff[1024];
    __shared__ int wsum[16], wpre[16];
    __shared__ int bbase;
    int tid = threadIdx.x;
    int lane = tid & 63, wid = tid >> 6;
    int b = blockIdx.x;          // 128 blocks
    int x = b & 7, j = b >> 3;
    int bucket = x * 16 + j;
    int lo = x * npb + j * npb2;
    int xhi = min((x + 1) * npb, n);
    int hi = min(lo + npb2, xhi);
    if (hi < lo) hi = lo;
    int nn = hi - lo;            // <= npb2 (782) <= 1024
    int cntb = gcount[bucket * 32];
    const int2* bp = bpairs + (size_t)bucket * cap;
    {
        int part = 0;
        for (int q = tid; q < bucket; q += 1024) part += gcount[q * 32];
        #pragma unroll
        for (int o = 1; o < 64; o <<= 1) part += __shfl_xor(part, o, 64);
        if (lane == 0) wsum[wid] = part;
    }
    ldeg[tid] = 0;
    __syncthreads();
    if (tid == 0) {
        int c = 0;
        #pragma unroll
        for (int w = 0; w < 16; ++w) c += wsum[w];
        bbase = c;
    }
    __syncthreads();
    for (int i = tid; i < cntb; i += 1024) atomicAdd(&ldeg[bp[i].y - lo], 1);
    __syncthreads();
    int v = (tid < nn) ? ldeg[tid] : 0;
    int s = v;
    #pragma unroll
    for (int o = 1; o < 64; o <<= 1) {
        int t = __shfl_up(s, o, 64);
        if (lane >= o) s += t;
    }
    if (lane == 63) wsum[wid] = s;
    __syncthreads();
    if (tid == 0) {
        int c = 0;
        #pragma unroll
        for (int w = 0; w < 16; ++w) { wpre[w] = c; c += wsum[w]; }
    }
    __syncthreads();
    int excl = wpre[wid] + s - v;
    int base = bbase;
    if (tid < nn) {
        loff[tid] = excl;
        off[lo + tid] = base + excl;
    }
    if (b == 0 && tid == 0) off[n] = e;
    __syncthreads();
    ldeg[tid] = 0;
    __syncthreads();
    for (int i = tid; i < cntb; i += 1024) {
        int2 p = bp[i];
        int k = p.y - lo;
        int slot = base + loff[k] + atomicAdd(&ldeg[k], 1);
        csr[slot] = p.x;
    }
}

// x -> bf16 table (sage x-path) + fp8 table (gather). 4 cols/thread.
__global__ void cvt_x_kernel(const float* __restrict__ in, uint32_t* __restrict__ bfout,
                             uint32_t* __restrict__ f8out, int n4) {
    int i = blockIdx.x * blockDim.x + threadIdx.x;
    if (i >= n4) return;
    float4 v = ((const float4*)in)[i];
    bfout[i * 2]     = pack_bf16(v.x, v.y);
    bfout[i * 2 + 1] = pack_bf16(v.z, v.w);
    f8out[i] = pack_fp8x4(v.x, v.y, v.z, v.w);
}

// Pack [Wn;Wr] into MFMA B-frag bf16 layout (see R5).
__global__ void pack_w_kernel(const float* __restrict__ Wn, const float* __restrict__ Wr,
                              uint32_t* __restrict__ packed) {
    int t = blockIdx.x * blockDim.x + threadIdx.x;  // 4096 threads
    if (t >= 4096) return;
    int lane = t & 63;
    int no = (t >> 6) & 7;
    int ko = t >> 9;
    int n = no * 16 + (lane & 15);
    int kbase = ko * 32 + ((lane >> 4) << 3);
    uint32_t v[4];
    #pragma unroll
    for (int jj = 0; jj < 4; ++jj) {
        int k0 = kbase + jj * 2, k1 = k0 + 1;
        float a = (k0 < 128) ? Wn[k0 * 128 + n] : Wr[(k0 - 128) * 128 + n];
        float b = (k1 < 128) ? Wn[k1 * 128 + n] : Wr[(k1 - 128) * 128 + n];
        v[jj] = pack_bf16(a, b);
    }
    uint4 u4; u4.x = v[0]; u4.y = v[1]; u4.z = v[2]; u4.w = v[3];
    ((uint4*)packed)[t] = u4;
}

// Pack Wc1 [128][64] f32 into B-frag layout
__global__ void pack_wc_kernel(const float* __restrict__ Wc1, uint32_t* __restrict__ packed) {
    int t = blockIdx.x * blockDim.x + threadIdx.x;  // 1024 threads
    if (t >= 1024) return;
    int lane = t & 63;
    int no = (t >> 6) & 3;
    int ko = t >> 8;
    int n = no * 16 + (lane & 15);
    int kbase = ko * 32 + ((lane >> 4) << 3);
    uint32_t v[4];
    #pragma unroll
    for (int jj = 0; jj < 4; ++jj) {
        int k0 = kbase + jj * 2;
        v[jj] = pack_bf16(Wc1[k0 * 64 + n], Wc1[(k0 + 1) * 64 + n]);
    }
    uint4 u4; u4.x = v[0]; u4.y = v[1]; u4.z = v[2]; u4.w = v[3];
    ((uint4*)packed)[t] = u4;
}

// one wave per node; fp8 rows (128B): 16 lanes x uint2 per row, 4 edges/group,
// unrolled x2 (8 edges/iter). f32x2 accumulators, packed decode+add.
__global__ __launch_bounds__(256) void aggregate_fp8_kernel(
    const uint32_t* __restrict__ f8, const int* __restrict__ off,
    const int* __restrict__ csr, uint32_t* __restrict__ outmean, int n) {
    int wv = (blockIdx.x * blockDim.x + threadIdx.x) >> 6;
    int lane = threadIdx.x & 63;
    if (wv >= n) return;
    int beg = off[wv], end = off[wv + 1];
    int len = end - beg;
    int sub = lane >> 4;   // which of 4 concurrent edges
    int c   = lane & 15;   // uint2 chunk: cols c*8 .. c*8+7
    const uint2* fp = (const uint2*)f8;  // row = 16 uint2
    f32x2 acc[4];
    #pragma unroll
    for (int k = 0; k < 4; ++k) acc[k] = (f32x2){0.f, 0.f};
    for (int base = 0; base < len; base += 64) {
        int m = len - base; if (m > 64) m = 64;
        int idx = csr[beg + base + (lane < m ? lane : 0)];
        for (int j0 = 0; j0 < m; j0 += 8) {           // wave-uniform trip count
            int ja = j0 + sub;
            int jb = j0 + 4 + sub;
            int sa = __shfl(idx, (ja < m ? ja : 0), 64);  // all lanes active
            int sb = __shfl(idx, (jb < m ? jb : 0), 64);
            bool pa = ja < m, pb = jb < m;
            uint2 ua, ub;
            if (pa) ua = fp[(size_t)sa * 16 + c];
            if (pb) ub = fp[(size_t)sb * 16 + c];
            if (pa) {
                add_fp8x4_v(&acc[0], &acc[1], ua.x);
                add_fp8x4_v(&acc[2], &acc[3], ua.y);
            }
            if (pb) {
                add_fp8x4_v(&acc[0], &acc[1], ub.x);
                add_fp8x4_v(&acc[2], &acc[3], ub.y);
            }
        }
    }
    // reduce across 4 sub-groups (lanes c, c+16, c+32, c+48), packed adds
    #pragma unroll
    for (int k = 0; k < 4; ++k) {
        f32x2 t;
        t.x = __shfl_xor(acc[k].x, 16, 64);
        t.y = __shfl_xor(acc[k].y, 16, 64);
        acc[k] += t;
        t.x = __shfl_xor(acc[k].x, 32, 64);
        t.y = __shfl_xor(acc[k].y, 32, 64);
        acc[k] += t;
    }
    float inv = 1.0f / fmaxf((float)len, 1.0f);
    // lane (c,sub) writes bf16 dword c*4+sub = cols c*8+2sub, c*8+2sub+1
    outmean[(size_t)wv * 64 + c * 4 + sub] =
        pack_bf16(acc[sub].x * inv, acc[sub].y * inv);
}

// h = [mean|x](bf16) @ Wpacked + b via MFMA; writes h_raw as BF16.
__global__ __launch_bounds__(256) void sage_mfma_kernel(
    const uint32_t* __restrict__ meanbf, const uint32_t* __restrict__ xbf,
    const uint32_t* __restrict__ Wp, const float* __restrict__ bias,
    unsigned short* __restrict__ hout, float* __restrict__ stats, int n) {
    __shared__ uint4 sW[4096];          // 64 KB packed weights
    __shared__ float redS[4][128];
    __shared__ float redQ[4][128];
    for (int i = threadIdx.x; i < 4096; i += 256) sW[i] = ((const uint4*)Wp)[i];
    __syncthreads();
    int lane = threadIdx.x & 63;
    int wid = threadIdx.x >> 6;
    int c = lane & 15;
    int kg = lane >> 4;
    float bcol[8];
    #pragma unroll
    for (int no = 0; no < 8; ++no) bcol[no] = bias[no * 16 + c];
    float ssum[8], ssq[8];
    #pragma unroll
    for (int no = 0; no < 8; ++no) { ssum[no] = 0.f; ssq[no] = 0.f; }
    int nstrips = n >> 4;
    int sstride = gridDim.x * 4;
    for (int strip = blockIdx.x * 4 + wid; strip < nstrips; strip += sstride) {
        const uint4* mrow = (const uint4*)(meanbf + (size_t)(strip * 16 + c) * 64);
        const uint4* xrow = (const uint4*)(xbf + (size_t)(strip * 16 + c) * 64);
        f32x4 acc[8];
        #pragma unroll
        for (int no = 0; no < 8; ++no) acc[no] = (f32x4){0.f, 0.f, 0.f, 0.f};
        #pragma unroll
        for (int ko = 0; ko < 8; ++ko) {
            FragU a;
            a.u = (ko < 4) ? mrow[ko * 4 + kg] : xrow[(ko - 4) * 4 + kg];
            #pragma unroll
            for (int no = 0; no < 8; ++no) {
                FragU b;
                b.u = sW[(ko * 8 + no) * 64 + lane];
                acc[no] = __builtin_amdgcn_mfma_f32_16x16x32_bf16(a.s, b.s, acc[no], 0, 0, 0);
            }
        }
        #pragma unroll
        for (int no = 0; no < 8; ++no) {
            #pragma unroll
            for (int r = 0; r < 4; ++r) {
                float v = acc[no][r] + bcol[no];
                int grow = strip * 16 + kg * 4 + r;
                hout[(size_t)grow * HID + no * 16 + c] = bf16_one(v);
                ssum[no] += v;
                ssq[no] += v * v;
            }
        }
    }
    #pragma unroll
    for (int no = 0; no < 8; ++no) {
        ssum[no] += __shfl_xor(ssum[no], 16, 64);
        ssum[no] += __shfl_xor(ssum[no], 32, 64);
        ssq[no]  += __shfl_xor(ssq[no], 16, 64);
        ssq[no]  += __shfl_xor(ssq[no], 32, 64);
    }
    if (lane < 16) {
        #pragma unroll
        for (int no = 0; no < 8; ++no) {
            redS[wid][no * 16 + lane] = ssum[no];
            redQ[wid][no * 16 + lane] = ssq[no];
        }
    }
    __syncthreads();
    if (threadIdx.x < 128) {
        float ts = redS[0][threadIdx.x] + redS[1][threadIdx.x] + redS[2][threadIdx.x] + redS[3][threadIdx.x];
        float tq = redQ[0][threadIdx.x] + redQ[1][threadIdx.x] + redQ[2][threadIdx.x] + redQ[3][threadIdx.x];
        atomicAdd(&stats[threadIdx.x], ts);
        atomicAdd(&stats[HID + threadIdx.x], tq);
    }
}

__global__ void bnparam_kernel(const float* __restrict__ stats, const float* __restrict__ g,
                               const float* __restrict__ be, float* __restrict__ params, float invn) {
    int j = threadIdx.x;  // 128
    float mu = stats[j] * invn;
    float var = stats[HID + j] * invn - mu * mu;
    float a = g[j] * rsqrtf(var + 1e-5f);
    params[j] = a;
    params[HID + j] = be[j] - mu * a;
}

// read bf16 h_raw (4 cols/thread), normalize+relu, write bf16 (+ optional fp8)
__global__ void norm_relu_kernel(const uint32_t* __restrict__ hraw, uint32_t* __restrict__ hbf,
                                 uint32_t* __restrict__ f8out, const float* __restrict__ params,
                                 int total4) {
    int i = blockIdx.x * blockDim.x + threadIdx.x;
    if (i >= total4) return;
    int cp = (i & 31) * 4;  // first col of this 4-col group
    uint2 u = ((const uint2*)hraw)[i];
    float v0 = __uint_as_float(u.x << 16);
    float v1 = __uint_as_float(u.x & 0xffff0000u);
    float v2 = __uint_as_float(u.y << 16);
    float v3 = __uint_as_float(u.y & 0xffff0000u);
    v0 = fmaxf(fmaf(v0, params[cp], params[HID + cp]), 0.f);
    v1 = fmaxf(fmaf(v1, params[cp + 1], params[HID + cp + 1]), 0.f);
    v2 = fmaxf(fmaf(v2, params[cp + 2], params[HID + cp + 2]), 0.f);
    v3 = fmaxf(fmaf(v3, params[cp + 3], params[HID + cp + 3]), 0.f);
    uint2 w;
    w.x = pack_bf16(v0, v1);
    w.y = pack_bf16(v2, v3);
    ((uint2*)hbf)[i] = w;
    if (f8out) f8out[i] = pack_fp8x4(v0, v1, v2, v3);
}

// classifier via MFMA: out = relu(hn@Wc1+bc1)@Wc2 + bc2.
__global__ __launch_bounds__(256) void classifier_mfma_kernel(
    const uint32_t* __restrict__ hnbf, const uint32_t* __restrict__ Wcp,
    const float* __restrict__ bc1, const float* __restrict__ Wc2,
    const float* __restrict__ bc2, float* __restrict__ out, int n) {
    __shared__ uint4 sW[1024];  // 16 KB packed Wc1
    for (int i = threadIdx.x; i < 1024; i += 256) sW[i] = ((const uint4*)Wcp)[i];
    __syncthreads();
    int lane = threadIdx.x & 63;
    int wid = threadIdx.x >> 6;
    int c = lane & 15;
    int kg = lane >> 4;
    float b1v[4], w2v[4];
    #pragma unroll
    for (int no = 0; no < 4; ++no) {
        b1v[no] = bc1[no * 16 + c];
        w2v[no] = Wc2[no * 16 + c];
    }
    float b2v = bc2[0];
    int nstrips = n >> 4;
    int sstride = gridDim.x * 4;
    for (int strip = blockIdx.x * 4 + wid; strip < nstrips; strip += sstride) {
        const uint4* hrow = (const uint4*)(hnbf + (size_t)(strip * 16 + c) * 64);
        f32x4 acc[4];
        #pragma unroll
        for (int no = 0; no < 4; ++no) acc[no] = (f32x4){0.f, 0.f, 0.f, 0.f};
        #pragma unroll
        for (int ko = 0; ko < 4; ++ko) {
            FragU a;
            a.u = hrow[ko * 4 + kg];
            #pragma unroll
            for (int no = 0; no < 4; ++no) {
                FragU b;
                b.u = sW[(ko * 4 + no) * 64 + lane];
                acc[no] = __builtin_amdgcn_mfma_f32_16x16x32_bf16(a.s, b.s, acc[no], 0, 0, 0);
            }
        }
        float p[4];
        #pragma unroll
        for (int r = 0; r < 4; ++r) {
            p[r] = 0.f;
            #pragma unroll
            for (int no = 0; no < 4; ++no)
                p[r] += fmaxf(acc[no][r] + b1v[no], 0.f) * w2v[no];
        }
        #pragma unroll
        for (int r = 0; r < 4; ++r) {
            p[r] += __shfl_xor(p[r], 1, 64);
            p[r] += __shfl_xor(p[r], 2, 64);
            p[r] += __shfl_xor(p[r], 4, 64);
            p[r] += __shfl_xor(p[r], 8, 64);
        }
        if (c == 0) {
            int row = strip * 16 + kg * 4;
            #pragma unroll
            for (int r = 0; r < 4; ++r) out[row + r] = p[r] + b2v;
        }
    }
}

extern "C" void kernel_launch(void* const* d_in, const int* in_sizes, int n_in,
                              void* d_out, int out_size, void* d_ws, size_t ws_size,
                              hipStream_t stream) {
    const float* x   = (const float*)d_in[0];
    const int*   ei  = (const int*)d_in[1];
    const float* Wn0 = (const float*)d_in[2];
    const float* b0  = (const float*)d_in[3];
    const float* Wr0 = (const float*)d_in[4];
    const float* g0  = (const float*)d_in[5];
    const float* be0 = (const float*)d_in[6];
    const float* Wn1 = (const float*)d_in[7];
    const float* b1  = (const float*)d_in[8];
    const float* Wr1 = (const float*)d_in[9];
    const float* g1  = (const float*)d_in[10];
    const float* be1 = (const float*)d_in[11];
    const float* Wc1 = (const float*)d_in[12];
    const float* bc1 = (const float*)d_in[13];
    const float* Wc2 = (const float*)d_in[14];
    const float* bc2 = (const float*)d_in[15];
    float* out = (float*)d_out;

    const int N = in_sizes[0] / HID;
    const int E = in_sizes[1] / 2;
    const int* srcv = ei;
    const int* tgtv = ei + E;

    size_t o = 0;
    auto carve = [&](size_t bytes) {
        void* p = (char*)d_ws + o;
        o += (bytes + 255) & ~(size_t)255;
        return p;
    };
    int* off       = (int*)carve((size_t)(N + 1) * 4);
    int* csr       = (int*)carve((size_t)E * 4);
    float* bufA    = (float*)carve((size_t)N * HID * 4);   // [mean0|h0raw] then [h1raw|-]
    float* bufB    = (float*)carve((size_t)N * HID * 4);   // bpairs, then mean1
    uint32_t* fbf  = (uint32_t*)carve((size_t)N * HID * 2);  // bf16: x, h0n, then h1n
    uint32_t* f8t  = (uint32_t*)carve((size_t)N * HID);      // fp8 gather table: x, then h0n
    uint32_t* Wp0  = (uint32_t*)carve(4096 * 16);
    uint32_t* Wp1  = (uint32_t*)carve(4096 * 16);
    uint32_t* Wcp  = (uint32_t*)carve(1024 * 16);
    int* gcount    = (int*)carve(NBKT * 128);  // counters padded to 128B lines
    float* stats0  = (float*)carve(256 * 4);
    float* stats1  = (float*)carve(256 * 4);
    float* params0 = (float*)carve(256 * 4);
    float* params1 = (float*)carve(256 * 4);
    (void)ws_size; (void)n_in; (void)out_size;

    uint32_t* mean0 = (uint32_t*)bufA;                          // bufA first half
    uint32_t* h0raw = (uint32_t*)bufA + (size_t)N * 64;         // bufA second half
    uint32_t* mean1 = (uint32_t*)bufB;                          // bpairs dead
    uint32_t* h1raw = (uint32_t*)bufA;                          // mean0 dead
    int2* bpairs    = (int2*)bufB;

    const int npb  = (N + 7) / 8;        // nodes per XCD range
    const int npb2 = (npb + 15) / 16;    // nodes per sub-bucket
    const int cap  = E / NBKT + 4096;    // per-bucket capacity (slack)

    hipMemsetAsync(gcount, 0, NBKT * 128, stream);
    hipMemsetAsync(stats0, 0, 256 * 4, stream);
    hipMemsetAsync(stats1, 0, 256 * 4, stream);

    int binblocks = (E + CHUNK - 1) / CHUNK;

    bin_kernel<<<binblocks, 256, 0, stream>>>(srcv, tgtv, gcount, bpairs, E, npb, npb2, cap);
    build_kernel<<<NBKT, 1024, 0, stream>>>(bpairs, gcount, off, csr, cap, npb, npb2, N, E);

    pack_w_kernel<<<16, 256, 0, stream>>>(Wn0, Wr0, Wp0);
    pack_w_kernel<<<16, 256, 0, stream>>>(Wn1, Wr1, Wp1);
    pack_wc_kernel<<<4, 256, 0, stream>>>(Wc1, Wcp);

    int aggblocks = (N * 64 + 255) / 256;
    int q4blocks  = (N * 32 + 255) / 256;
    float invn = 1.0f / (float)N;

    // layer 0
    cvt_x_kernel<<<q4blocks, 256, 0, stream>>>(x, fbf, f8t, N * 32);
    aggregate_fp8_kernel<<<aggblocks, 256, 0, stream>>>(f8t, off, csr, mean0, N);
    sage_mfma_kernel<<<256, 256, 0, stream>>>(mean0, fbf, Wp0, b0, (unsigned short*)h0raw, stats0, N);
    bnparam_kernel<<<1, 128, 0, stream>>>(stats0, g0, be0, params0, invn);
    norm_relu_kernel<<<q4blocks, 256, 0, stream>>>(h0raw, fbf, f8t, params0, N * 32);

    // layer 1
    aggregate_fp8_kernel<<<aggblocks, 256, 0, stream>>>(f8t, off, csr, mean1, N);
    sage_mfma_kernel<<<256, 256, 0, stream>>>(mean1, fbf, Wp1, b1, (unsigned short*)h1raw, stats1, N);
    bnparam_kernel<<<1, 128, 0, stream>>>(stats1, g1, be1, params1, invn);
    norm_relu_kernel<<<q4blocks, 256, 0, stream>>>(h1raw, fbf, nullptr, params1, N * 32);

    // classifier (reads bf16 h1 from fbf)
    classifier_mfma_kernel<<<256, 256, 0, stream>>>(fbf, Wcp, bc1, Wc2, bc2, out, N);
}

// Round 19
// 304.247 us; speedup vs baseline: 1.0794x; 1.0583x over previous
//
#include <hip/hip_runtime.h>
#include <hip/hip_bf16.h>

// GraphSAGE 2-layer + BN + ReLU + MLP classifier.
// R19: bpairs packed to ONE uint32 (src 17b | tgt_local 10b << 17) — halves
//      bin write + build 2x read (~64MB saved). CHUNK 3072 (fewer blocks).
//      Aggregate/sage/classifier = R18 (aggregate declared at its knee).

#define HID 128
#define CHUNK 3072   // 256 threads x 12 edges
#define NBKT 128     // total sub-buckets (8 XCD ranges x 16)

typedef __attribute__((ext_vector_type(8))) short short8;
typedef __attribute__((ext_vector_type(4))) float f32x4;
typedef __attribute__((ext_vector_type(2))) float f32x2;

union FragU { uint4 u; short8 s; };

#if defined(__has_builtin)
#if __has_builtin(__builtin_amdgcn_cvt_pk_f32_fp8) && __has_builtin(__builtin_amdgcn_cvt_pk_fp8_f32)
#define HAVE_FP8_CVT 1
#endif
#endif

__device__ inline uint32_t pack_bf16(float a, float b) {
    uint32_t ua = __float_as_uint(a);
    uint32_t ub = __float_as_uint(b);
    ua = ua + 0x7fffu + ((ua >> 16) & 1u);  // RNE
    ub = ub + 0x7fffu + ((ub >> 16) & 1u);
    return (ua >> 16) | (ub & 0xffff0000u);
}

__device__ inline unsigned short bf16_one(float a) {
    uint32_t u = __float_as_uint(a);
    u = u + 0x7fffu + ((u >> 16) & 1u);
    return (unsigned short)(u >> 16);
}

// ---- fp8 e4m3fn encode/decode ----
__device__ inline unsigned char enc_e4m3(float f) {
    unsigned char s = (f < 0.f) ? 0x80 : 0;
    float a = fabsf(f);
    if (a >= 448.f) return s | 0x7E;
    if (a < 9.765625e-4f) return s;  // < 2^-10 -> 0
    int e; float m = frexpf(a, &e);  // a = m*2^e, m in [0.5,1)
    int E = e + 6;
    if (E <= 0) {
        int m3 = (int)rintf(ldexpf(a, 9));
        if (m3 > 7) return s | 0x08;
        return s | (unsigned char)m3;
    }
    int m3 = (int)rintf((m - 0.5f) * 16.f);
    if (m3 == 8) { E += 1; m3 = 0; if (E >= 16) return s | 0x7E; }
    return s | (unsigned char)((E << 3) | m3);
}

__device__ inline float dec_e4m3(unsigned char u) {
    int E = (u >> 3) & 0xF, m = u & 7;
    float v = E ? __uint_as_float((uint32_t)(((E + 120) << 23) | (m << 20)))
                : (float)m * 1.953125e-3f;
    return (u & 0x80) ? -v : v;
}

__device__ inline uint32_t pack_fp8x4(float a, float b, float c, float d) {
#ifdef HAVE_FP8_CVT
    int r = 0;
    r = __builtin_amdgcn_cvt_pk_fp8_f32(a, b, r, false);
    r = __builtin_amdgcn_cvt_pk_fp8_f32(c, d, r, true);
    return (uint32_t)r;
#else
    return (uint32_t)enc_e4m3(a) | ((uint32_t)enc_e4m3(b) << 8) |
           ((uint32_t)enc_e4m3(c) << 16) | ((uint32_t)enc_e4m3(d) << 24);
#endif
}

// decode one dword (4 fp8) and accumulate into two f32x2 (fully packed path)
__device__ inline void add_fp8x4_v(f32x2* a0, f32x2* a1, uint32_t u) {
#ifdef HAVE_FP8_CVT
    f32x2 lo = __builtin_amdgcn_cvt_pk_f32_fp8((int)u, false);
    f32x2 hi = __builtin_amdgcn_cvt_pk_f32_fp8((int)u, true);
    *a0 += lo;
    *a1 += hi;
#else
    f32x2 lo = {dec_e4m3(u & 255), dec_e4m3((u >> 8) & 255)};
    f32x2 hi = {dec_e4m3((u >> 16) & 255), dec_e4m3(u >> 24)};
    *a0 += lo;
    *a1 += hi;
#endif
}

// ---- phase 1: bin edges into 128 node-range buckets (packed u32 pairs) ----
// word = src (17b) | tgt_local (10b) << 17 ; tgt_local = t - bucket_lo < 782
__global__ __launch_bounds__(256) void bin_kernel(
    const int* __restrict__ src, const int* __restrict__ tgt,
    int* __restrict__ gcount, uint32_t* __restrict__ bpairs,
    int e, int npb, int npb2, int cap) {
    __shared__ uint32_t pairs[CHUNK];
    __shared__ unsigned char bkt[CHUNK];
    __shared__ int lcnt[NBKT], lbase[NBKT], lpos[NBKT];
    int tid = threadIdx.x;
    if (tid < NBKT) { lcnt[tid] = 0; lpos[tid] = 0; }
    __syncthreads();
    int chunk0 = blockIdx.x * CHUNK;
    #pragma unroll
    for (int j = 0; j < 12; ++j) {
        int k = tid + j * 256;
        int idx = chunk0 + k;
        if (idx < e) {
            int s = src[idx];
            int t = tgt[idx];
            int x = t / npb;
            int rem = t - x * npb;
            int jj = rem / npb2;
            if (jj > 15) jj = 15;
            int b = x * 16 + jj;
            int tl = rem - jj * npb2;     // < npb2 <= 782 < 1024
            pairs[k] = (uint32_t)s | ((uint32_t)tl << 17);
            bkt[k] = (unsigned char)b;
            atomicAdd(&lcnt[b], 1);
        }
    }
    __syncthreads();
    if (tid < NBKT) lbase[tid] = atomicAdd(&gcount[tid * 32], lcnt[tid]);
    __syncthreads();
    #pragma unroll
    for (int j = 0; j < 12; ++j) {
        int k = tid + j * 256;
        int idx = chunk0 + k;
        if (idx < e) {
            int b = bkt[k];
            int r = atomicAdd(&lpos[b], 1);
            bpairs[(size_t)b * cap + lbase[b] + r] = pairs[k];
        }
    }
}

// ---- phase 2: one 1024-thread block per bucket; LDS hist+scan -> off, csr ----
__global__ __launch_bounds__(1024) void build_kernel(
    const uint32_t* __restrict__ bpairs, const int* __restrict__ gcount,
    int* __restrict__ off, int* __restrict__ csr,
    int cap, int npb, int npb2, int n, int e) {
    __shared__ int ldeg[1024];
    __shared__ int loff[1024];
    __shared__ int wsum[16], wpre[16];
    __shared__ int bbase;
    int tid = threadIdx.x;
    int lane = tid & 63, wid = tid >> 6;
    int b = blockIdx.x;          // 128 blocks
    int x = b & 7, j = b >> 3;
    int bucket = x * 16 + j;
    int lo = x * npb + j * npb2;
    int xhi = min((x + 1) * npb, n);
    int hi = min(lo + npb2, xhi);
    if (hi < lo) hi = lo;
    int nn = hi - lo;            // <= npb2 (782) <= 1024
    int cntb = gcount[bucket * 32];
    const uint32_t* bp = bpairs + (size_t)bucket * cap;
    {
        int part = 0;
        for (int q = tid; q < bucket; q += 1024) part += gcount[q * 32];
        #pragma unroll
        for (int o = 1; o < 64; o <<= 1) part += __shfl_xor(part, o, 64);
        if (lane == 0) wsum[wid] = part;
    }
    ldeg[tid] = 0;
    __syncthreads();
    if (tid == 0) {
        int c = 0;
        #pragma unroll
        for (int w = 0; w < 16; ++w) c += wsum[w];
        bbase = c;
    }
    __syncthreads();
    // pass A: LDS degree histogram (tgt_local = word >> 17)
    for (int i = tid; i < cntb; i += 1024) atomicAdd(&ldeg[bp[i] >> 17], 1);
    __syncthreads();
    int v = (tid < nn) ? ldeg[tid] : 0;
    int s = v;
    #pragma unroll
    for (int o = 1; o < 64; o <<= 1) {
        int t = __shfl_up(s, o, 64);
        if (lane >= o) s += t;
    }
    if (lane == 63) wsum[wid] = s;
    __syncthreads();
    if (tid == 0) {
        int c = 0;
        #pragma unroll
        for (int w = 0; w < 16; ++w) { wpre[w] = c; c += wsum[w]; }
    }
    __syncthreads();
    int excl = wpre[wid] + s - v;
    int base = bbase;
    if (tid < nn) {
        loff[tid] = excl;
        off[lo + tid] = base + excl;
    }
    if (b == 0 && tid == 0) off[n] = e;
    __syncthreads();
    ldeg[tid] = 0;
    __syncthreads();
    // pass B: scatter csr using LDS counters (no global atomics)
    for (int i = tid; i < cntb; i += 1024) {
        uint32_t w = bp[i];
        int k = w >> 17;
        int slot = base + loff[k] + atomicAdd(&ldeg[k], 1);
        csr[slot] = (int)(w & 0x1FFFFu);
    }
}

// x -> bf16 table (sage x-path) + fp8 table (gather). 4 cols/thread.
__global__ void cvt_x_kernel(const float* __restrict__ in, uint32_t* __restrict__ bfout,
                             uint32_t* __restrict__ f8out, int n4) {
    int i = blockIdx.x * blockDim.x + threadIdx.x;
    if (i >= n4) return;
    float4 v = ((const float4*)in)[i];
    bfout[i * 2]     = pack_bf16(v.x, v.y);
    bfout[i * 2 + 1] = pack_bf16(v.z, v.w);
    f8out[i] = pack_fp8x4(v.x, v.y, v.z, v.w);
}

// Pack [Wn;Wr] into MFMA B-frag bf16 layout (see R5).
__global__ void pack_w_kernel(const float* __restrict__ Wn, const float* __restrict__ Wr,
                              uint32_t* __restrict__ packed) {
    int t = blockIdx.x * blockDim.x + threadIdx.x;  // 4096 threads
    if (t >= 4096) return;
    int lane = t & 63;
    int no = (t >> 6) & 7;
    int ko = t >> 9;
    int n = no * 16 + (lane & 15);
    int kbase = ko * 32 + ((lane >> 4) << 3);
    uint32_t v[4];
    #pragma unroll
    for (int jj = 0; jj < 4; ++jj) {
        int k0 = kbase + jj * 2, k1 = k0 + 1;
        float a = (k0 < 128) ? Wn[k0 * 128 + n] : Wr[(k0 - 128) * 128 + n];
        float b = (k1 < 128) ? Wn[k1 * 128 + n] : Wr[(k1 - 128) * 128 + n];
        v[jj] = pack_bf16(a, b);
    }
    uint4 u4; u4.x = v[0]; u4.y = v[1]; u4.z = v[2]; u4.w = v[3];
    ((uint4*)packed)[t] = u4;
}

// Pack Wc1 [128][64] f32 into B-frag layout
__global__ void pack_wc_kernel(const float* __restrict__ Wc1, uint32_t* __restrict__ packed) {
    int t = blockIdx.x * blockDim.x + threadIdx.x;  // 1024 threads
    if (t >= 1024) return;
    int lane = t & 63;
    int no = (t >> 6) & 3;
    int ko = t >> 8;
    int n = no * 16 + (lane & 15);
    int kbase = ko * 32 + ((lane >> 4) << 3);
    uint32_t v[4];
    #pragma unroll
    for (int jj = 0; jj < 4; ++jj) {
        int k0 = kbase + jj * 2;
        v[jj] = pack_bf16(Wc1[k0 * 64 + n], Wc1[(k0 + 1) * 64 + n]);
    }
    uint4 u4; u4.x = v[0]; u4.y = v[1]; u4.z = v[2]; u4.w = v[3];
    ((uint4*)packed)[t] = u4;
}

// one wave per node; fp8 rows (128B): 16 lanes x uint2 per row, 4 edges/group,
// unrolled x2 (8 edges/iter). f32x2 accumulators, packed decode+add.
__global__ __launch_bounds__(256) void aggregate_fp8_kernel(
    const uint32_t* __restrict__ f8, const int* __restrict__ off,
    const int* __restrict__ csr, uint32_t* __restrict__ outmean, int n) {
    int wv = (blockIdx.x * blockDim.x + threadIdx.x) >> 6;
    int lane = threadIdx.x & 63;
    if (wv >= n) return;
    int beg = off[wv], end = off[wv + 1];
    int len = end - beg;
    int sub = lane >> 4;   // which of 4 concurrent edges
    int c   = lane & 15;   // uint2 chunk: cols c*8 .. c*8+7
    const uint2* fp = (const uint2*)f8;  // row = 16 uint2
    f32x2 acc[4];
    #pragma unroll
    for (int k = 0; k < 4; ++k) acc[k] = (f32x2){0.f, 0.f};
    for (int base = 0; base < len; base += 64) {
        int m = len - base; if (m > 64) m = 64;
        int idx = csr[beg + base + (lane < m ? lane : 0)];
        for (int j0 = 0; j0 < m; j0 += 8) {           // wave-uniform trip count
            int ja = j0 + sub;
            int jb = j0 + 4 + sub;
            int sa = __shfl(idx, (ja < m ? ja : 0), 64);  // all lanes active
            int sb = __shfl(idx, (jb < m ? jb : 0), 64);
            bool pa = ja < m, pb = jb < m;
            uint2 ua, ub;
            if (pa) ua = fp[(size_t)sa * 16 + c];
            if (pb) ub = fp[(size_t)sb * 16 + c];
            if (pa) {
                add_fp8x4_v(&acc[0], &acc[1], ua.x);
                add_fp8x4_v(&acc[2], &acc[3], ua.y);
            }
            if (pb) {
                add_fp8x4_v(&acc[0], &acc[1], ub.x);
                add_fp8x4_v(&acc[2], &acc[3], ub.y);
            }
        }
    }
    #pragma unroll
    for (int k = 0; k < 4; ++k) {
        f32x2 t;
        t.x = __shfl_xor(acc[k].x, 16, 64);
        t.y = __shfl_xor(acc[k].y, 16, 64);
        acc[k] += t;
        t.x = __shfl_xor(acc[k].x, 32, 64);
        t.y = __shfl_xor(acc[k].y, 32, 64);
        acc[k] += t;
    }
    float inv = 1.0f / fmaxf((float)len, 1.0f);
    outmean[(size_t)wv * 64 + c * 4 + sub] =
        pack_bf16(acc[sub].x * inv, acc[sub].y * inv);
}

// h = [mean|x](bf16) @ Wpacked + b via MFMA; writes h_raw as BF16.
__global__ __launch_bounds__(256) void sage_mfma_kernel(
    const uint32_t* __restrict__ meanbf, const uint32_t* __restrict__ xbf,
    const uint32_t* __restrict__ Wp, const float* __restrict__ bias,
    unsigned short* __restrict__ hout, float* __restrict__ stats, int n) {
    __shared__ uint4 sW[4096];          // 64 KB packed weights
    __shared__ float redS[4][128];
    __shared__ float redQ[4][128];
    for (int i = threadIdx.x; i < 4096; i += 256) sW[i] = ((const uint4*)Wp)[i];
    __syncthreads();
    int lane = threadIdx.x & 63;
    int wid = threadIdx.x >> 6;
    int c = lane & 15;
    int kg = lane >> 4;
    float bcol[8];
    #pragma unroll
    for (int no = 0; no < 8; ++no) bcol[no] = bias[no * 16 + c];
    float ssum[8], ssq[8];
    #pragma unroll
    for (int no = 0; no < 8; ++no) { ssum[no] = 0.f; ssq[no] = 0.f; }
    int nstrips = n >> 4;
    int sstride = gridDim.x * 4;
    for (int strip = blockIdx.x * 4 + wid; strip < nstrips; strip += sstride) {
        const uint4* mrow = (const uint4*)(meanbf + (size_t)(strip * 16 + c) * 64);
        const uint4* xrow = (const uint4*)(xbf + (size_t)(strip * 16 + c) * 64);
        f32x4 acc[8];
        #pragma unroll
        for (int no = 0; no < 8; ++no) acc[no] = (f32x4){0.f, 0.f, 0.f, 0.f};
        #pragma unroll
        for (int ko = 0; ko < 8; ++ko) {
            FragU a;
            a.u = (ko < 4) ? mrow[ko * 4 + kg] : xrow[(ko - 4) * 4 + kg];
            #pragma unroll
            for (int no = 0; no < 8; ++no) {
                FragU b;
                b.u = sW[(ko * 8 + no) * 64 + lane];
                acc[no] = __builtin_amdgcn_mfma_f32_16x16x32_bf16(a.s, b.s, acc[no], 0, 0, 0);
            }
        }
        #pragma unroll
        for (int no = 0; no < 8; ++no) {
            #pragma unroll
            for (int r = 0; r < 4; ++r) {
                float v = acc[no][r] + bcol[no];
                int grow = strip * 16 + kg * 4 + r;
                hout[(size_t)grow * HID + no * 16 + c] = bf16_one(v);
                ssum[no] += v;
                ssq[no] += v * v;
            }
        }
    }
    #pragma unroll
    for (int no = 0; no < 8; ++no) {
        ssum[no] += __shfl_xor(ssum[no], 16, 64);
        ssum[no] += __shfl_xor(ssum[no], 32, 64);
        ssq[no]  += __shfl_xor(ssq[no], 16, 64);
        ssq[no]  += __shfl_xor(ssq[no], 32, 64);
    }
    if (lane < 16) {
        #pragma unroll
        for (int no = 0; no < 8; ++no) {
            redS[wid][no * 16 + lane] = ssum[no];
            redQ[wid][no * 16 + lane] = ssq[no];
        }
    }
    __syncthreads();
    if (threadIdx.x < 128) {
        float ts = redS[0][threadIdx.x] + redS[1][threadIdx.x] + redS[2][threadIdx.x] + redS[3][threadIdx.x];
        float tq = redQ[0][threadIdx.x] + redQ[1][threadIdx.x] + redQ[2][threadIdx.x] + redQ[3][threadIdx.x];
        atomicAdd(&stats[threadIdx.x], ts);
        atomicAdd(&stats[HID + threadIdx.x], tq);
    }
}

__global__ void bnparam_kernel(const float* __restrict__ stats, const float* __restrict__ g,
                               const float* __restrict__ be, float* __restrict__ params, float invn) {
    int j = threadIdx.x;  // 128
    float mu = stats[j] * invn;
    float var = stats[HID + j] * invn - mu * mu;
    float a = g[j] * rsqrtf(var + 1e-5f);
    params[j] = a;
    params[HID + j] = be[j] - mu * a;
}

// read bf16 h_raw (4 cols/thread), normalize+relu, write bf16 (+ optional fp8)
__global__ void norm_relu_kernel(const uint32_t* __restrict__ hraw, uint32_t* __restrict__ hbf,
                                 uint32_t* __restrict__ f8out, const float* __restrict__ params,
                                 int total4) {
    int i = blockIdx.x * blockDim.x + threadIdx.x;
    if (i >= total4) return;
    int cp = (i & 31) * 4;  // first col of this 4-col group
    uint2 u = ((const uint2*)hraw)[i];
    float v0 = __uint_as_float(u.x << 16);
    float v1 = __uint_as_float(u.x & 0xffff0000u);
    float v2 = __uint_as_float(u.y << 16);
    float v3 = __uint_as_float(u.y & 0xffff0000u);
    v0 = fmaxf(fmaf(v0, params[cp], params[HID + cp]), 0.f);
    v1 = fmaxf(fmaf(v1, params[cp + 1], params[HID + cp + 1]), 0.f);
    v2 = fmaxf(fmaf(v2, params[cp + 2], params[HID + cp + 2]), 0.f);
    v3 = fmaxf(fmaf(v3, params[cp + 3], params[HID + cp + 3]), 0.f);
    uint2 w;
    w.x = pack_bf16(v0, v1);
    w.y = pack_bf16(v2, v3);
    ((uint2*)hbf)[i] = w;
    if (f8out) f8out[i] = pack_fp8x4(v0, v1, v2, v3);
}

// classifier via MFMA: out = relu(hn@Wc1+bc1)@Wc2 + bc2.
__global__ __launch_bounds__(256) void classifier_mfma_kernel(
    const uint32_t* __restrict__ hnbf, const uint32_t* __restrict__ Wcp,
    const float* __restrict__ bc1, const float* __restrict__ Wc2,
    const float* __restrict__ bc2, float* __restrict__ out, int n) {
    __shared__ uint4 sW[1024];  // 16 KB packed Wc1
    for (int i = threadIdx.x; i < 1024; i += 256) sW[i] = ((const uint4*)Wcp)[i];
    __syncthreads();
    int lane = threadIdx.x & 63;
    int wid = threadIdx.x >> 6;
    int c = lane & 15;
    int kg = lane >> 4;
    float b1v[4], w2v[4];
    #pragma unroll
    for (int no = 0; no < 4; ++no) {
        b1v[no] = bc1[no * 16 + c];
        w2v[no] = Wc2[no * 16 + c];
    }
    float b2v = bc2[0];
    int nstrips = n >> 4;
    int sstride = gridDim.x * 4;
    for (int strip = blockIdx.x * 4 + wid; strip < nstrips; strip += sstride) {
        const uint4* hrow = (const uint4*)(hnbf + (size_t)(strip * 16 + c) * 64);
        f32x4 acc[4];
        #pragma unroll
        for (int no = 0; no < 4; ++no) acc[no] = (f32x4){0.f, 0.f, 0.f, 0.f};
        #pragma unroll
        for (int ko = 0; ko < 4; ++ko) {
            FragU a;
            a.u = hrow[ko * 4 + kg];
            #pragma unroll
            for (int no = 0; no < 4; ++no) {
                FragU b;
                b.u = sW[(ko * 4 + no) * 64 + lane];
                acc[no] = __builtin_amdgcn_mfma_f32_16x16x32_bf16(a.s, b.s, acc[no], 0, 0, 0);
            }
        }
        float p[4];
        #pragma unroll
        for (int r = 0; r < 4; ++r) {
            p[r] = 0.f;
            #pragma unroll
            for (int no = 0; no < 4; ++no)
                p[r] += fmaxf(acc[no][r] + b1v[no], 0.f) * w2v[no];
        }
        #pragma unroll
        for (int r = 0; r < 4; ++r) {
            p[r] += __shfl_xor(p[r], 1, 64);
            p[r] += __shfl_xor(p[r], 2, 64);
            p[r] += __shfl_xor(p[r], 4, 64);
            p[r] += __shfl_xor(p[r], 8, 64);
        }
        if (c == 0) {
            int row = strip * 16 + kg * 4;
            #pragma unroll
            for (int r = 0; r < 4; ++r) out[row + r] = p[r] + b2v;
        }
    }
}

extern "C" void kernel_launch(void* const* d_in, const int* in_sizes, int n_in,
                              void* d_out, int out_size, void* d_ws, size_t ws_size,
                              hipStream_t stream) {
    const float* x   = (const float*)d_in[0];
    const int*   ei  = (const int*)d_in[1];
    const float* Wn0 = (const float*)d_in[2];
    const float* b0  = (const float*)d_in[3];
    const float* Wr0 = (const float*)d_in[4];
    const float* g0  = (const float*)d_in[5];
    const float* be0 = (const float*)d_in[6];
    const float* Wn1 = (const float*)d_in[7];
    const float* b1  = (const float*)d_in[8];
    const float* Wr1 = (const float*)d_in[9];
    const float* g1  = (const float*)d_in[10];
    const float* be1 = (const float*)d_in[11];
    const float* Wc1 = (const float*)d_in[12];
    const float* bc1 = (const float*)d_in[13];
    const float* Wc2 = (const float*)d_in[14];
    const float* bc2 = (const float*)d_in[15];
    float* out = (float*)d_out;

    const int N = in_sizes[0] / HID;
    const int E = in_sizes[1] / 2;
    const int* srcv = ei;
    const int* tgtv = ei + E;

    size_t o = 0;
    auto carve = [&](size_t bytes) {
        void* p = (char*)d_ws + o;
        o += (bytes + 255) & ~(size_t)255;
        return p;
    };
    int* off       = (int*)carve((size_t)(N + 1) * 4);
    int* csr       = (int*)carve((size_t)E * 4);
    float* bufA    = (float*)carve((size_t)N * HID * 4);   // [mean0|h0raw] then [h1raw|-]
    float* bufB    = (float*)carve((size_t)N * HID * 4);   // bpairs, then mean1
    uint32_t* fbf  = (uint32_t*)carve((size_t)N * HID * 2);  // bf16: x, h0n, then h1n
    uint32_t* f8t  = (uint32_t*)carve((size_t)N * HID);      // fp8 gather table: x, then h0n
    uint32_t* Wp0  = (uint32_t*)carve(4096 * 16);
    uint32_t* Wp1  = (uint32_t*)carve(4096 * 16);
    uint32_t* Wcp  = (uint32_t*)carve(1024 * 16);
    int* gcount    = (int*)carve(NBKT * 128);  // counters padded to 128B lines
    float* stats0  = (float*)carve(256 * 4);
    float* stats1  = (float*)carve(256 * 4);
    float* params0 = (float*)carve(256 * 4);
    float* params1 = (float*)carve(256 * 4);
    (void)ws_size; (void)n_in; (void)out_size;

    uint32_t* mean0 = (uint32_t*)bufA;                          // bufA first half
    uint32_t* h0raw = (uint32_t*)bufA + (size_t)N * 64;         // bufA second half
    uint32_t* mean1 = (uint32_t*)bufB;                          // bpairs dead
    uint32_t* h1raw = (uint32_t*)bufA;                          // mean0 dead
    uint32_t* bpairs = (uint32_t*)bufB;                         // packed u32 pairs

    const int npb  = (N + 7) / 8;        // nodes per XCD range
    const int npb2 = (npb + 15) / 16;    // nodes per sub-bucket (<= 782 < 1024)
    const int cap  = E / NBKT + 4096;    // per-bucket capacity (slack)
    // bpairs bytes = 128*cap*4 ~= 14.9MB <= bufB 51.2MB

    hipMemsetAsync(gcount, 0, NBKT * 128, stream);
    hipMemsetAsync(stats0, 0, 256 * 4, stream);
    hipMemsetAsync(stats1, 0, 256 * 4, stream);

    int binblocks = (E + CHUNK - 1) / CHUNK;

    bin_kernel<<<binblocks, 256, 0, stream>>>(srcv, tgtv, gcount, bpairs, E, npb, npb2, cap);
    build_kernel<<<NBKT, 1024, 0, stream>>>(bpairs, gcount, off, csr, cap, npb, npb2, N, E);

    pack_w_kernel<<<16, 256, 0, stream>>>(Wn0, Wr0, Wp0);
    pack_w_kernel<<<16, 256, 0, stream>>>(Wn1, Wr1, Wp1);
    pack_wc_kernel<<<4, 256, 0, stream>>>(Wc1, Wcp);

    int aggblocks = (N * 64 + 255) / 256;
    int q4blocks  = (N * 32 + 255) / 256;
    float invn = 1.0f / (float)N;

    // layer 0
    cvt_x_kernel<<<q4blocks, 256, 0, stream>>>(x, fbf, f8t, N * 32);
    aggregate_fp8_kernel<<<aggblocks, 256, 0, stream>>>(f8t, off, csr, mean0, N);
    sage_mfma_kernel<<<256, 256, 0, stream>>>(mean0, fbf, Wp0, b0, (unsigned short*)h0raw, stats0, N);
    bnparam_kernel<<<1, 128, 0, stream>>>(stats0, g0, be0, params0, invn);
    norm_relu_kernel<<<q4blocks, 256, 0, stream>>>(h0raw, fbf, f8t, params0, N * 32);

    // layer 1
    aggregate_fp8_kernel<<<aggblocks, 256, 0, stream>>>(f8t, off, csr, mean1, N);
    sage_mfma_kernel<<<256, 256, 0, stream>>>(mean1, fbf, Wp1, b1, (unsigned short*)h1raw, stats1, N);
    bnparam_kernel<<<1, 128, 0, stream>>>(stats1, g1, be1, params1, invn);
    norm_relu_kernel<<<q4blocks, 256, 0, stream>>>(h1raw, fbf, nullptr, params1, N * 32);

    // classifier (reads bf16 h1 from fbf)
    classifier_mfma_kernel<<<256, 256, 0, stream>>>(fbf, Wcp, bc1, Wc2, bc2, out, N);
}